// Round 4
// baseline (945.037 us; speedup 1.0000x reference)
//
#include <hip/hip_runtime.h>

typedef unsigned short u16;
typedef unsigned int u32;
typedef __attribute__((ext_vector_type(8))) __bf16 bf16x8;
typedef __attribute__((ext_vector_type(4))) float f32x4;

#define SLEN 4096
#define HIDDEN 2304
#define NHEADS 8
#define NKVH 4
#define HDIM 256
#define WINDOW 2048

__device__ __forceinline__ u16 f2b(float x) {
  u32 u = __float_as_uint(x);
  u32 r = (u + 0x7fffu + ((u >> 16) & 1u)) >> 16;  // RNE, finite inputs only
  return (u16)r;
}

__device__ __forceinline__ void load_lds16(const void* g, void* l) {
  __builtin_amdgcn_global_load_lds((const __attribute__((address_space(1))) u32*)g,
                                   (__attribute__((address_space(3))) u32*)l,
                                   16, 0, 0);
}

// ---------------- fp32 -> bf16 convert ----------------
__global__ __launch_bounds__(256) void k_f2b(const float* __restrict__ in,
                                             u16* __restrict__ out, int n4) {
  int i = blockIdx.x * 256 + threadIdx.x;
  if (i >= n4) return;
  float4 v = ((const float4*)in)[i];
  ushort4 o;
  o.x = f2b(v.x); o.y = f2b(v.y); o.z = f2b(v.z); o.w = f2b(v.w);
  ((ushort4*)out)[i] = o;
}

// ---------------- GEMM: C[M][N] = A[M][K] * B[N][K]^T (bf16 in, fp32 out) ----
template<int M, int N, int K>
__global__ __launch_bounds__(256) void gemm_bt(const u16* __restrict__ A,
                                               const u16* __restrict__ B,
                                               float* __restrict__ C) {
  constexpr int NTN = N / 128;
  __shared__ u16 As[128 * 32];
  __shared__ u16 Bs[128 * 32];
  const int tid = threadIdx.x;
  const int lane = tid & 63;
  const int w = tid >> 6;
  const int wr = (w >> 1) * 64, wc = (w & 1) * 64;
  const int l15 = lane & 15, l4 = lane >> 4;
  const size_t m0 = (size_t)(blockIdx.x / NTN) * 128;
  const size_t n0 = (size_t)(blockIdx.x % NTN) * 128;
  const int r = tid >> 2;
  const int cbe = (tid & 3) * 8;
  const u16* Ag = A + (m0 + r) * K + cbe;
  const u16* Bg = B + (n0 + r) * K + cbe;
  char* Asb = (char*)As + w * 1024;
  char* Bsb = (char*)Bs + w * 1024;
  f32x4 acc[4][4];
#pragma unroll
  for (int i = 0; i < 4; ++i)
#pragma unroll
    for (int j = 0; j < 4; ++j) { f32x4 z = {0.f, 0.f, 0.f, 0.f}; acc[i][j] = z; }

  for (int kt = 0; kt < K; kt += 32) {
    load_lds16(Ag + kt, Asb);
    load_lds16(Ag + kt + (size_t)64 * K, Asb + 4096);
    load_lds16(Bg + kt, Bsb);
    load_lds16(Bg + kt + (size_t)64 * K, Bsb + 4096);
    __syncthreads();
    bf16x8 a[4], b[4];
#pragma unroll
    for (int mi = 0; mi < 4; ++mi)
      a[mi] = *(const bf16x8*)&As[(wr + mi * 16 + l15) * 32 + l4 * 8];
#pragma unroll
    for (int ni = 0; ni < 4; ++ni)
      b[ni] = *(const bf16x8*)&Bs[(wc + ni * 16 + l15) * 32 + l4 * 8];
#pragma unroll
    for (int mi = 0; mi < 4; ++mi)
#pragma unroll
      for (int ni = 0; ni < 4; ++ni)
        acc[mi][ni] = __builtin_amdgcn_mfma_f32_16x16x32_bf16(a[mi], b[ni], acc[mi][ni], 0, 0, 0);
    __syncthreads();
  }
#pragma unroll
  for (int mi = 0; mi < 4; ++mi) {
#pragma unroll
    for (int ni = 0; ni < 4; ++ni) {
      size_t row = m0 + wr + mi * 16 + l4 * 4;
      size_t col = n0 + wc + ni * 16 + l15;
      float* Cp = C + row * N + col;
#pragma unroll
      for (int j = 0; j < 4; ++j) Cp[(size_t)j * N] = acc[mi][ni][j];
    }
  }
}

// ---------------- RoPE + split into per-head bf16 Q/K ----------------
__global__ __launch_bounds__(256) void k_rope(const float* __restrict__ qkv,
                                              u16* __restrict__ Qb, u16* __restrict__ Kb) {
  const int s = blockIdx.x;
  const float* row = qkv + (size_t)s * 4096;
  const float pos = (float)s;
  const int tid = threadIdx.x;
  for (int idx = tid; idx < 1536; idx += 256) {
    int h = idx >> 7;
    int d = idx & 127;
    float inv = expf((float)d * -0.07195578415987644f);  // -ln(10000)/128
    float ang = pos * inv;
    float sn, c;
    sincosf(ang, &sn, &c);
    int colbase = (h < 8) ? (h << 8) : (2048 + ((h - 8) << 8));
    float x1 = row[colbase + d];
    float x2 = row[colbase + d + 128];
    float o1 = x1 * c - x2 * sn;
    float o2 = x2 * c + x1 * sn;
    u16* dst = (h < 8) ? (Qb + ((size_t)h * SLEN + s) * HDIM)
                       : (Kb + ((size_t)(h - 8) * SLEN + s) * HDIM);
    dst[d] = f2b(o1);
    dst[d + 128] = f2b(o2);
  }
}

// ---------------- V transpose: qkv fp32 [s][3072+h*256+d] -> Vt bf16 [h][d][s]
__global__ __launch_bounds__(256) void k_vt(const float* __restrict__ qkv,
                                            u16* __restrict__ Vt) {
  __shared__ u16 t[64][272];  // 64 s-rows x 256 d, padded
  const int tid = threadIdx.x;
  const int h = blockIdx.y;
  const int s0 = blockIdx.x * 64;
#pragma unroll
  for (int pass = 0; pass < 16; ++pass) {
    int r = pass * 4 + (tid >> 6);
    int c4 = (tid & 63) * 4;
    float4 v = *(const float4*)(qkv + (size_t)(s0 + r) * 4096 + 3072 + h * 256 + c4);
    t[r][c4] = f2b(v.x); t[r][c4 + 1] = f2b(v.y);
    t[r][c4 + 2] = f2b(v.z); t[r][c4 + 3] = f2b(v.w);
  }
  __syncthreads();
#pragma unroll
  for (int i = 0; i < 8; ++i) {
    int chunk = i * 256 + tid;
    int d = chunk >> 3;
    int s8 = (chunk & 7) * 8;
    u16 tmp[8];
#pragma unroll
    for (int j = 0; j < 8; ++j) tmp[j] = t[s8 + j][d];
    uint4 o;
    o.x = (u32)tmp[0] | ((u32)tmp[1] << 16);
    o.y = (u32)tmp[2] | ((u32)tmp[3] << 16);
    o.z = (u32)tmp[4] | ((u32)tmp[5] << 16);
    o.w = (u32)tmp[6] | ((u32)tmp[7] << 16);
    *(uint4*)(Vt + ((size_t)h * HDIM + d) * SLEN + s0 + s8) = o;
  }
}

// ---------------- flash attention: barrier-free, 1 wave / 16 q-rows ----------
// K and Vt fragments loaded directly from global (L1/L2-resident tiles).
__global__ __launch_bounds__(64, 2) void k_attn(const u16* __restrict__ Qb,
                                                const u16* __restrict__ Kb,
                                                const u16* __restrict__ Vt,
                                                u16* __restrict__ AO) {
  __shared__ char pbuf[2048];  // P [16 q][64 k] bf16, XOR-swizzled
  const int lane = threadIdx.x & 63;
  const int l15 = lane & 15, l4 = lane >> 4;
  const int h = blockIdx.y;
  const int q0 = blockIdx.x * 16;
  const u16* Qh = Qb + (size_t)h * SLEN * HDIM;
  const u16* Kh = Kb + (size_t)(h >> 1) * SLEN * HDIM;
  const u16* Vth = Vt + (size_t)(h >> 1) * HDIM * SLEN;

  bf16x8 qa[8];
  {
    const u16* qrow = Qh + (size_t)(q0 + l15) * HDIM + l4 * 8;
#pragma unroll
    for (int ks = 0; ks < 8; ++ks) qa[ks] = *(const bf16x8*)(qrow + ks * 32);
  }
  f32x4 O[16];
#pragma unroll
  for (int i = 0; i < 16; ++i) { f32x4 z = {0.f, 0.f, 0.f, 0.f}; O[i] = z; }
  // softcapped scores in (-50,50): m init -50 keeps fully-masked tiles exact-0.
  float mrow[4] = {-50.f, -50.f, -50.f, -50.f};
  float lrow[4] = {0.f, 0.f, 0.f, 0.f};

  const int t_lo = (q0 >= WINDOW) ? ((q0 - (WINDOW - 1)) >> 6) : 0;
  const int t_hi = q0 >> 6;
  for (int t = t_lo; t <= t_hi; ++t) {
    const int k0 = t * 64;
    // ---- S = Q K^T (K fragments direct from global) ----
    f32x4 sc[4];
#pragma unroll
    for (int n = 0; n < 4; ++n) { f32x4 z = {0.f, 0.f, 0.f, 0.f}; sc[n] = z; }
#pragma unroll
    for (int ks = 0; ks < 8; ++ks) {
#pragma unroll
      for (int n = 0; n < 4; ++n) {
        bf16x8 kb = *(const bf16x8*)(Kh + (size_t)(k0 + n * 16 + l15) * HDIM + ks * 32 + l4 * 8);
        sc[n] = __builtin_amdgcn_mfma_f32_16x16x32_bf16(qa[ks], kb, sc[n], 0, 0, 0);
      }
    }
    // ---- scale, softcap, mask, online softmax ----
    const bool need_mask = (k0 + 63 > q0) || (k0 < q0 - 2032);
    const int i_base = q0 + l4 * 4;
    const int k_base = k0 + l15;
    float rmax[4] = {-1e30f, -1e30f, -1e30f, -1e30f};
#pragma unroll
    for (int n = 0; n < 4; ++n) {
#pragma unroll
      for (int j = 0; j < 4; ++j) {
        // y = 50*tanh(s*SCALE/50); SCALE=0.0625 -> exp arg = s*0.0025
        float t2 = __expf(sc[n][j] * 0.0025f);
        float y = 50.f - 100.f / (t2 + 1.f);
        if (need_mask) {
          int ig = i_base + j;
          int kg = k_base + n * 16;
          if (kg > ig || kg < ig - (WINDOW - 1)) y = -1e9f;
        }
        sc[n][j] = y;
        rmax[j] = fmaxf(rmax[j], y);
      }
    }
#pragma unroll
    for (int j = 0; j < 4; ++j) {
      rmax[j] = fmaxf(rmax[j], __shfl_xor(rmax[j], 1));
      rmax[j] = fmaxf(rmax[j], __shfl_xor(rmax[j], 2));
      rmax[j] = fmaxf(rmax[j], __shfl_xor(rmax[j], 4));
      rmax[j] = fmaxf(rmax[j], __shfl_xor(rmax[j], 8));
    }
    f32x4 ev;
    float pm[4];
#pragma unroll
    for (int j = 0; j < 4; ++j) {
      float mn = fmaxf(mrow[j], rmax[j]);
      ev[j] = __expf(mrow[j] - mn);
      mrow[j] = mn;
      pm[j] = mn;
    }
    float rsum[4] = {0.f, 0.f, 0.f, 0.f};
#pragma unroll
    for (int n = 0; n < 4; ++n)
#pragma unroll
      for (int j = 0; j < 4; ++j) {
        float pv = __expf(sc[n][j] - pm[j]);
        sc[n][j] = pv;
        rsum[j] += pv;
      }
#pragma unroll
    for (int j = 0; j < 4; ++j) {
      rsum[j] += __shfl_xor(rsum[j], 1);
      rsum[j] += __shfl_xor(rsum[j], 2);
      rsum[j] += __shfl_xor(rsum[j], 4);
      rsum[j] += __shfl_xor(rsum[j], 8);
      lrow[j] = lrow[j] * ev[j] + rsum[j];
    }
#pragma unroll
    for (int i = 0; i < 16; ++i) O[i] *= ev;

    // ---- P -> LDS (swizzled), then O += P * V (Vt fragments from global) ----
#pragma unroll
    for (int n = 0; n < 4; ++n)
#pragma unroll
      for (int j = 0; j < 4; ++j) {
        int prow = l4 * 4 + j;
        int a = (prow * 128 + (n * 16 + l15) * 2) ^ ((prow & 7) << 4);
        *(u16*)(pbuf + a) = f2b(sc[n][j]);
      }
#pragma unroll
    for (int ks2 = 0; ks2 < 2; ++ks2) {
      int a = (l15 * 128 + ks2 * 64 + l4 * 16) ^ ((l15 & 7) << 4);
      bf16x8 pa = *(const bf16x8*)(pbuf + a);
#pragma unroll
      for (int nn = 0; nn < 16; ++nn) {
        bf16x8 vb = *(const bf16x8*)(Vth + (size_t)(nn * 16 + l15) * SLEN + k0 + ks2 * 32 + l4 * 8);
        O[nn] = __builtin_amdgcn_mfma_f32_16x16x32_bf16(pa, vb, O[nn], 0, 0, 0);
      }
    }
  }
  // ---- normalize + store bf16 [4096][2048] ----
  f32x4 linv;
#pragma unroll
  for (int j = 0; j < 4; ++j) linv[j] = 1.f / lrow[j];
  const size_t orow = (size_t)(q0 + l4 * 4);
#pragma unroll
  for (int nn = 0; nn < 16; ++nn) {
    f32x4 o = O[nn] * linv;
#pragma unroll
    for (int j = 0; j < 4; ++j)
      AO[(orow + j) * 2048 + h * 256 + nn * 16 + l15] = f2b(o[j]);
  }
}

// ---------------- launch ----------------
// Workspace layout with aliasing (peak ~115 MB):
//   [0      , 18.9MB)  hid_b   (dead after GEMM1)   } reused by Qv/Kv/Vt
//   [18.9MB , 37.8MB)  wqkv_b  (dead after GEMM1)   }   (33.6MB total)
//   [37.8MB , 47.2MB)  wo_b    (live until GEMM2)
//   [47.2MB , 114.3MB) qkv fp32 (dead after rope/vt) } reused by AO (16.8MB)
extern "C" void kernel_launch(void* const* d_in, const int* in_sizes, int n_in,
                              void* d_out, int out_size, void* d_ws, size_t ws_size,
                              hipStream_t stream) {
  (void)in_sizes; (void)n_in; (void)out_size; (void)ws_size;
  const float* hidden = (const float*)d_in[0];
  // d_in[1] attention_mask: sliding-window causal, computed inline -> unused
  // d_in[2] position_ids: arange(S) -> unused
  const float* Wqkv = (const float*)d_in[3];
  const float* Wo = (const float*)d_in[4];

  char* base = (char*)d_ws;
  const size_t SZ_HID = (size_t)SLEN * HIDDEN * 2;
  const size_t SZ_WQKV = (size_t)4096 * HIDDEN * 2;
  const size_t SZ_WO = (size_t)HIDDEN * 2048 * 2;
  const size_t SZ_Q = (size_t)NHEADS * SLEN * HDIM * 2;
  const size_t SZ_K = (size_t)NKVH * SLEN * HDIM * 2;

  u16* hid_b = (u16*)base;
  u16* wqkv_b = (u16*)(base + SZ_HID);
  u16* wo_b = (u16*)(base + SZ_HID + SZ_WQKV);
  float* qkv = (float*)(base + SZ_HID + SZ_WQKV + SZ_WO);
  u16* Qv = (u16*)base;                  // over hid_b (dead after GEMM1)
  u16* Kv = (u16*)(base + SZ_Q);         // over hid_b/wqkv_b
  u16* Vt = (u16*)(base + SZ_Q + SZ_K);  // over wqkv_b
  u16* AO = (u16*)qkv;                   // over qkv (dead after rope/vt)

  k_f2b<<<SLEN * HIDDEN / 4 / 256, 256, 0, stream>>>(hidden, hid_b, SLEN * HIDDEN / 4);
  k_f2b<<<4096 * HIDDEN / 4 / 256, 256, 0, stream>>>(Wqkv, wqkv_b, 4096 * HIDDEN / 4);
  k_f2b<<<HIDDEN * 2048 / 4 / 256, 256, 0, stream>>>(Wo, wo_b, HIDDEN * 2048 / 4);

  gemm_bt<4096, 4096, 2304><<<dim3(32 * 32), 256, 0, stream>>>(hid_b, wqkv_b, qkv);
  k_rope<<<SLEN, 256, 0, stream>>>(qkv, Qv, Kv);
  k_vt<<<dim3(64, NKVH), 256, 0, stream>>>(qkv, Vt);
  k_attn<<<dim3(256, NHEADS), 64, 0, stream>>>(Qv, Kv, Vt, AO);
  gemm_bt<4096, 2304, 2048><<<dim3(32 * 18), 256, 0, stream>>>(AO, wo_b, (float*)d_out);
}

// Round 5
// 798.626 us; speedup vs baseline: 1.1833x; 1.1833x over previous
//
#include <hip/hip_runtime.h>

typedef unsigned short u16;
typedef unsigned int u32;
typedef __attribute__((ext_vector_type(8))) __bf16 bf16x8;
typedef __attribute__((ext_vector_type(4))) float f32x4;

#define SLEN 4096
#define HIDDEN 2304
#define NHEADS 8
#define NKVH 4
#define HDIM 256
#define WINDOW 2048

__device__ __forceinline__ u16 f2b(float x) {
  u32 u = __float_as_uint(x);
  u32 r = (u + 0x7fffu + ((u >> 16) & 1u)) >> 16;  // RNE, finite inputs only
  return (u16)r;
}

__device__ __forceinline__ void load_lds16(const void* g, void* l) {
  __builtin_amdgcn_global_load_lds((const __attribute__((address_space(1))) u32*)g,
                                   (__attribute__((address_space(3))) u32*)l,
                                   16, 0, 0);
}

// ---------------- fp32 -> bf16 convert ----------------
__global__ __launch_bounds__(256) void k_f2b(const float* __restrict__ in,
                                             u16* __restrict__ out, int n4) {
  int i = blockIdx.x * 256 + threadIdx.x;
  if (i >= n4) return;
  float4 v = ((const float4*)in)[i];
  ushort4 o;
  o.x = f2b(v.x); o.y = f2b(v.y); o.z = f2b(v.z); o.w = f2b(v.w);
  ((ushort4*)out)[i] = o;
}

// ---------------- GEMM: C[M][N] = A[M][K] * B[N][K]^T (bf16 in, fp32 out) ----
template<int M, int N, int K>
__global__ __launch_bounds__(256) void gemm_bt(const u16* __restrict__ A,
                                               const u16* __restrict__ B,
                                               float* __restrict__ C) {
  constexpr int NTN = N / 128;
  __shared__ u16 As[128 * 32];
  __shared__ u16 Bs[128 * 32];
  const int tid = threadIdx.x;
  const int lane = tid & 63;
  const int w = tid >> 6;
  const int wr = (w >> 1) * 64, wc = (w & 1) * 64;
  const int l15 = lane & 15, l4 = lane >> 4;
  const size_t m0 = (size_t)(blockIdx.x / NTN) * 128;
  const size_t n0 = (size_t)(blockIdx.x % NTN) * 128;
  const int r = tid >> 2;
  const int cbe = (tid & 3) * 8;
  const u16* Ag = A + (m0 + r) * K + cbe;
  const u16* Bg = B + (n0 + r) * K + cbe;
  char* Asb = (char*)As + w * 1024;
  char* Bsb = (char*)Bs + w * 1024;
  f32x4 acc[4][4];
#pragma unroll
  for (int i = 0; i < 4; ++i)
#pragma unroll
    for (int j = 0; j < 4; ++j) { f32x4 z = {0.f, 0.f, 0.f, 0.f}; acc[i][j] = z; }

  for (int kt = 0; kt < K; kt += 32) {
    load_lds16(Ag + kt, Asb);
    load_lds16(Ag + kt + (size_t)64 * K, Asb + 4096);
    load_lds16(Bg + kt, Bsb);
    load_lds16(Bg + kt + (size_t)64 * K, Bsb + 4096);
    __syncthreads();
    bf16x8 a[4], b[4];
#pragma unroll
    for (int mi = 0; mi < 4; ++mi)
      a[mi] = *(const bf16x8*)&As[(wr + mi * 16 + l15) * 32 + l4 * 8];
#pragma unroll
    for (int ni = 0; ni < 4; ++ni)
      b[ni] = *(const bf16x8*)&Bs[(wc + ni * 16 + l15) * 32 + l4 * 8];
#pragma unroll
    for (int mi = 0; mi < 4; ++mi)
#pragma unroll
      for (int ni = 0; ni < 4; ++ni)
        acc[mi][ni] = __builtin_amdgcn_mfma_f32_16x16x32_bf16(a[mi], b[ni], acc[mi][ni], 0, 0, 0);
    __syncthreads();
  }
#pragma unroll
  for (int mi = 0; mi < 4; ++mi) {
#pragma unroll
    for (int ni = 0; ni < 4; ++ni) {
      size_t row = m0 + wr + mi * 16 + l4 * 4;
      size_t col = n0 + wc + ni * 16 + l15;
      float* Cp = C + row * N + col;
#pragma unroll
      for (int j = 0; j < 4; ++j) Cp[(size_t)j * N] = acc[mi][ni][j];
    }
  }
}

// ---------------- RoPE + split into per-head bf16 Q/K ----------------
__global__ __launch_bounds__(256) void k_rope(const float* __restrict__ qkv,
                                              u16* __restrict__ Qb, u16* __restrict__ Kb) {
  const int s = blockIdx.x;
  const float* row = qkv + (size_t)s * 4096;
  const float pos = (float)s;
  const int tid = threadIdx.x;
  for (int idx = tid; idx < 1536; idx += 256) {
    int h = idx >> 7;
    int d = idx & 127;
    float inv = expf((float)d * -0.07195578415987644f);  // -ln(10000)/128
    float ang = pos * inv;
    float sn, c;
    sincosf(ang, &sn, &c);
    int colbase = (h < 8) ? (h << 8) : (2048 + ((h - 8) << 8));
    float x1 = row[colbase + d];
    float x2 = row[colbase + d + 128];
    float o1 = x1 * c - x2 * sn;
    float o2 = x2 * c + x1 * sn;
    u16* dst = (h < 8) ? (Qb + ((size_t)h * SLEN + s) * HDIM)
                       : (Kb + ((size_t)(h - 8) * SLEN + s) * HDIM);
    dst[d] = f2b(o1);
    dst[d + 128] = f2b(o2);
  }
}

// ---------------- V transpose: qkv fp32 [s][3072+h*256+d] -> Vt bf16 [h][d][s]
__global__ __launch_bounds__(256) void k_vt(const float* __restrict__ qkv,
                                            u16* __restrict__ Vt) {
  __shared__ u16 t[64][272];  // 64 s-rows x 256 d, padded
  const int tid = threadIdx.x;
  const int h = blockIdx.y;
  const int s0 = blockIdx.x * 64;
#pragma unroll
  for (int pass = 0; pass < 16; ++pass) {
    int r = pass * 4 + (tid >> 6);
    int c4 = (tid & 63) * 4;
    float4 v = *(const float4*)(qkv + (size_t)(s0 + r) * 4096 + 3072 + h * 256 + c4);
    t[r][c4] = f2b(v.x); t[r][c4 + 1] = f2b(v.y);
    t[r][c4 + 2] = f2b(v.z); t[r][c4 + 3] = f2b(v.w);
  }
  __syncthreads();
#pragma unroll
  for (int i = 0; i < 8; ++i) {
    int chunk = i * 256 + tid;
    int d = chunk >> 3;
    int s8 = (chunk & 7) * 8;
    u16 tmp[8];
#pragma unroll
    for (int j = 0; j < 8; ++j) tmp[j] = t[s8 + j][d];
    uint4 o;
    o.x = (u32)tmp[0] | ((u32)tmp[1] << 16);
    o.y = (u32)tmp[2] | ((u32)tmp[3] << 16);
    o.z = (u32)tmp[4] | ((u32)tmp[5] << 16);
    o.w = (u32)tmp[6] | ((u32)tmp[7] << 16);
    *(uint4*)(Vt + ((size_t)h * HDIM + d) * SLEN + s0 + s8) = o;
  }
}

// ---------------- flash attention: barrier-free, 1 wave / 16 q-rows ----------
// Flattened grid with h in the LOW bits: linear id = q_tile*8 + head, so the
// round-robin block->CU mapping gives each CU q-tiles spread by 32 positions
// across the sliding-window cost ramp (per-CU work 184-212 tile-units, +-7%,
// vs 8-264 with the (x=q_tile, y=head) grid).
__global__ __launch_bounds__(64, 2) void k_attn(const u16* __restrict__ Qb,
                                                const u16* __restrict__ Kb,
                                                const u16* __restrict__ Vt,
                                                u16* __restrict__ AO) {
  __shared__ char pbuf[2048];  // P [16 q][64 k] bf16, XOR-swizzled
  const int lane = threadIdx.x & 63;
  const int l15 = lane & 15, l4 = lane >> 4;
  const int id = blockIdx.x;
  const int h = id & 7;
  const int q0 = (id >> 3) * 16;
  const u16* Qh = Qb + (size_t)h * SLEN * HDIM;
  const u16* Kh = Kb + (size_t)(h >> 1) * SLEN * HDIM;
  const u16* Vth = Vt + (size_t)(h >> 1) * HDIM * SLEN;

  bf16x8 qa[8];
  {
    const u16* qrow = Qh + (size_t)(q0 + l15) * HDIM + l4 * 8;
#pragma unroll
    for (int ks = 0; ks < 8; ++ks) qa[ks] = *(const bf16x8*)(qrow + ks * 32);
  }
  f32x4 O[16];
#pragma unroll
  for (int i = 0; i < 16; ++i) { f32x4 z = {0.f, 0.f, 0.f, 0.f}; O[i] = z; }
  // softcapped scores in (-50,50): m init -50 keeps fully-masked tiles exact-0.
  float mrow[4] = {-50.f, -50.f, -50.f, -50.f};
  float lrow[4] = {0.f, 0.f, 0.f, 0.f};

  const int t_lo = (q0 >= WINDOW) ? ((q0 - (WINDOW - 1)) >> 6) : 0;
  const int t_hi = q0 >> 6;
  for (int t = t_lo; t <= t_hi; ++t) {
    const int k0 = t * 64;
    // ---- S = Q K^T (K fragments direct from global) ----
    f32x4 sc[4];
#pragma unroll
    for (int n = 0; n < 4; ++n) { f32x4 z = {0.f, 0.f, 0.f, 0.f}; sc[n] = z; }
#pragma unroll
    for (int ks = 0; ks < 8; ++ks) {
#pragma unroll
      for (int n = 0; n < 4; ++n) {
        bf16x8 kb = *(const bf16x8*)(Kh + (size_t)(k0 + n * 16 + l15) * HDIM + ks * 32 + l4 * 8);
        sc[n] = __builtin_amdgcn_mfma_f32_16x16x32_bf16(qa[ks], kb, sc[n], 0, 0, 0);
      }
    }
    // ---- scale, softcap, mask, online softmax ----
    const bool need_mask = (k0 + 63 > q0) || (k0 < q0 - 2032);
    const int i_base = q0 + l4 * 4;
    const int k_base = k0 + l15;
    float rmax[4] = {-1e30f, -1e30f, -1e30f, -1e30f};
#pragma unroll
    for (int n = 0; n < 4; ++n) {
#pragma unroll
      for (int j = 0; j < 4; ++j) {
        // y = 50*tanh(s*SCALE/50); SCALE=0.0625 -> exp arg = s*0.0025
        float t2 = __expf(sc[n][j] * 0.0025f);
        float y = 50.f - 100.f / (t2 + 1.f);
        if (need_mask) {
          int ig = i_base + j;
          int kg = k_base + n * 16;
          if (kg > ig || kg < ig - (WINDOW - 1)) y = -1e9f;
        }
        sc[n][j] = y;
        rmax[j] = fmaxf(rmax[j], y);
      }
    }
#pragma unroll
    for (int j = 0; j < 4; ++j) {
      rmax[j] = fmaxf(rmax[j], __shfl_xor(rmax[j], 1));
      rmax[j] = fmaxf(rmax[j], __shfl_xor(rmax[j], 2));
      rmax[j] = fmaxf(rmax[j], __shfl_xor(rmax[j], 4));
      rmax[j] = fmaxf(rmax[j], __shfl_xor(rmax[j], 8));
    }
    f32x4 ev;
    float pm[4];
#pragma unroll
    for (int j = 0; j < 4; ++j) {
      float mn = fmaxf(mrow[j], rmax[j]);
      ev[j] = __expf(mrow[j] - mn);
      mrow[j] = mn;
      pm[j] = mn;
    }
    float rsum[4] = {0.f, 0.f, 0.f, 0.f};
#pragma unroll
    for (int n = 0; n < 4; ++n)
#pragma unroll
      for (int j = 0; j < 4; ++j) {
        float pv = __expf(sc[n][j] - pm[j]);
        sc[n][j] = pv;
        rsum[j] += pv;
      }
#pragma unroll
    for (int j = 0; j < 4; ++j) {
      rsum[j] += __shfl_xor(rsum[j], 1);
      rsum[j] += __shfl_xor(rsum[j], 2);
      rsum[j] += __shfl_xor(rsum[j], 4);
      rsum[j] += __shfl_xor(rsum[j], 8);
      lrow[j] = lrow[j] * ev[j] + rsum[j];
    }
#pragma unroll
    for (int i = 0; i < 16; ++i) O[i] *= ev;

    // ---- P -> LDS (swizzled), then O += P * V (Vt fragments from global) ----
#pragma unroll
    for (int n = 0; n < 4; ++n)
#pragma unroll
      for (int j = 0; j < 4; ++j) {
        int prow = l4 * 4 + j;
        int a = (prow * 128 + (n * 16 + l15) * 2) ^ ((prow & 7) << 4);
        *(u16*)(pbuf + a) = f2b(sc[n][j]);
      }
#pragma unroll
    for (int ks2 = 0; ks2 < 2; ++ks2) {
      int a = (l15 * 128 + ks2 * 64 + l4 * 16) ^ ((l15 & 7) << 4);
      bf16x8 pa = *(const bf16x8*)(pbuf + a);
#pragma unroll
      for (int nn = 0; nn < 16; ++nn) {
        bf16x8 vb = *(const bf16x8*)(Vth + (size_t)(nn * 16 + l15) * SLEN + k0 + ks2 * 32 + l4 * 8);
        O[nn] = __builtin_amdgcn_mfma_f32_16x16x32_bf16(pa, vb, O[nn], 0, 0, 0);
      }
    }
  }
  // ---- normalize + store bf16 [4096][2048] ----
  f32x4 linv;
#pragma unroll
  for (int j = 0; j < 4; ++j) linv[j] = 1.f / lrow[j];
  const size_t orow = (size_t)(q0 + l4 * 4);
#pragma unroll
  for (int nn = 0; nn < 16; ++nn) {
    f32x4 o = O[nn] * linv;
#pragma unroll
    for (int j = 0; j < 4; ++j)
      AO[(orow + j) * 2048 + h * 256 + nn * 16 + l15] = f2b(o[j]);
  }
}

// ---------------- launch ----------------
// Workspace layout with aliasing (peak ~115 MB):
//   [0      , 18.9MB)  hid_b   (dead after GEMM1)   } reused by Qv/Kv/Vt
//   [18.9MB , 37.8MB)  wqkv_b  (dead after GEMM1)   }   (33.6MB total)
//   [37.8MB , 47.2MB)  wo_b    (live until GEMM2)
//   [47.2MB , 114.3MB) qkv fp32 (dead after rope/vt) } reused by AO (16.8MB)
extern "C" void kernel_launch(void* const* d_in, const int* in_sizes, int n_in,
                              void* d_out, int out_size, void* d_ws, size_t ws_size,
                              hipStream_t stream) {
  (void)in_sizes; (void)n_in; (void)out_size; (void)ws_size;
  const float* hidden = (const float*)d_in[0];
  // d_in[1] attention_mask: sliding-window causal, computed inline -> unused
  // d_in[2] position_ids: arange(S) -> unused
  const float* Wqkv = (const float*)d_in[3];
  const float* Wo = (const float*)d_in[4];

  char* base = (char*)d_ws;
  const size_t SZ_HID = (size_t)SLEN * HIDDEN * 2;
  const size_t SZ_WQKV = (size_t)4096 * HIDDEN * 2;
  const size_t SZ_WO = (size_t)HIDDEN * 2048 * 2;
  const size_t SZ_Q = (size_t)NHEADS * SLEN * HDIM * 2;
  const size_t SZ_K = (size_t)NKVH * SLEN * HDIM * 2;

  u16* hid_b = (u16*)base;
  u16* wqkv_b = (u16*)(base + SZ_HID);
  u16* wo_b = (u16*)(base + SZ_HID + SZ_WQKV);
  float* qkv = (float*)(base + SZ_HID + SZ_WQKV + SZ_WO);
  u16* Qv = (u16*)base;                  // over hid_b (dead after GEMM1)
  u16* Kv = (u16*)(base + SZ_Q);         // over hid_b/wqkv_b
  u16* Vt = (u16*)(base + SZ_Q + SZ_K);  // over wqkv_b
  u16* AO = (u16*)qkv;                   // over qkv (dead after rope/vt)

  k_f2b<<<SLEN * HIDDEN / 4 / 256, 256, 0, stream>>>(hidden, hid_b, SLEN * HIDDEN / 4);
  k_f2b<<<4096 * HIDDEN / 4 / 256, 256, 0, stream>>>(Wqkv, wqkv_b, 4096 * HIDDEN / 4);
  k_f2b<<<HIDDEN * 2048 / 4 / 256, 256, 0, stream>>>(Wo, wo_b, HIDDEN * 2048 / 4);

  gemm_bt<4096, 4096, 2304><<<dim3(32 * 32), 256, 0, stream>>>(hid_b, wqkv_b, qkv);
  k_rope<<<SLEN, 256, 0, stream>>>(qkv, Qv, Kv);
  k_vt<<<dim3(64, NKVH), 256, 0, stream>>>(qkv, Vt);
  k_attn<<<dim3(256 * NHEADS), 64, 0, stream>>>(Qv, Kv, Vt, AO);
  gemm_bt<4096, 2304, 2048><<<dim3(32 * 18), 256, 0, stream>>>(AO, wo_b, (float*)d_out);
}